// Round 7
// baseline (135.921 us; speedup 1.0000x reference)
//
#include <hip/hip_runtime.h>

typedef __bf16 bf16x8 __attribute__((ext_vector_type(8)));
typedef float f32x4 __attribute__((ext_vector_type(4)));
typedef unsigned short u16x8 __attribute__((ext_vector_type(8)));
typedef unsigned short u16x4 __attribute__((ext_vector_type(4)));

__device__ inline unsigned short f2bf(float f) {
    __bf16 h = (__bf16)f;
    return __builtin_bit_cast(unsigned short, h);
}

__device__ inline unsigned int pkbf(float lo, float hi) {
    return (unsigned int)f2bf(lo) | ((unsigned int)f2bf(hi) << 16);
}

__device__ inline float fexp2(float x) {
#if __has_builtin(__builtin_amdgcn_exp2f)
    return __builtin_amdgcn_exp2f(x);
#else
    return exp2f(x);
#endif
}

__device__ inline f32x4 mfma16(u16x8 a, u16x8 b, f32x4 c) {
    return __builtin_amdgcn_mfma_f32_16x16x32_bf16(
        __builtin_bit_cast(bf16x8, a), __builtin_bit_cast(bf16x8, b), c, 0, 0, 0);
}

// async global->LDS, 16B per lane; LDS dest is wave-uniform base (+lane*16 by HW)
__device__ inline void gld_lds16(const unsigned short* gsrc, unsigned short* ldst) {
    __builtin_amdgcn_global_load_lds(
        (const __attribute__((address_space(1))) unsigned int*)gsrc,
        (__attribute__((address_space(3))) unsigned int*)ldst, 16, 0, 0);
}

// ---------------- elementwise f32 -> bf16 ----------------
__global__ __launch_bounds__(256) void cvt_f32_bf16(const float* __restrict__ in,
                                                    unsigned short* __restrict__ out, long n) {
    long i = ((long)blockIdx.x * blockDim.x + threadIdx.x) * 4;
    if (i >= n) return;
    float4 v = *(const float4*)(in + i);
    ushort4 r;
    r.x = f2bf(v.x); r.y = f2bf(v.y); r.z = f2bf(v.z); r.w = f2bf(v.w);
    *(ushort4*)(out + i) = r;
}

// ---------------- weight transposes ----------------
// WqkvT rows: 0-511 = Wq^T * qscale, 512-1023 = Wk^T, 1024-1535 = Wv^T. WoT: Wo^T.
__global__ __launch_bounds__(256) void prep_weights(const float* __restrict__ Wq,
                                                    const float* __restrict__ Wkv,
                                                    const float* __restrict__ Wo,
                                                    unsigned short* __restrict__ WqkvT,
                                                    unsigned short* __restrict__ WoT,
                                                    float qscale) {
    int idx = blockIdx.x * 256 + threadIdx.x;
    const int NQKV = 1536 * 512;
    if (idx < NQKV) {
        int n = idx >> 9, kk = idx & 511;
        float v;
        if (n < 512) v = Wq[kk * 512 + n] * qscale;
        else         v = Wkv[kk * 1024 + (n - 512)];
        WqkvT[idx] = f2bf(v);
    } else {
        int j = idx - NQKV;
        int n = j >> 9, kk = j & 511;
        WoT[j] = f2bf(Wo[kk * 512 + n]);
    }
}

// ---------------- GEMM: C[m][n] = sum_k A[m][k] * Bt[n][k] ----------------
// 128x128 tile, BK=32, 4 waves, double-buffered linear LDS, global_load_lds staging.
template<int WRITE_BF16, int MASKED>
__global__ __launch_bounds__(256) void gemm_bt(const unsigned short* __restrict__ A,
                                               const unsigned short* __restrict__ Bt,
                                               void* __restrict__ Cv,
                                               int M, int N, int K,
                                               const int* __restrict__ mask) {
    __shared__ unsigned short AsL[2][128 * 32];
    __shared__ unsigned short BsL[2][128 * 32];
    const int tid = threadIdx.x;
    const int lane = tid & 63;
    const int wid = tid >> 6;
    const int lg = lane >> 4, lr = lane & 15;
    const int wm = wid >> 1, wn = wid & 1;
    const long m0 = (long)blockIdx.y * 128, n0 = (long)blockIdx.x * 128;

    f32x4 acc[4][4] = {};

    const unsigned short* aS0 = A  + (m0 + (tid >> 2)) * K + (tid & 3) * 8;
    const unsigned short* aS1 = A  + (m0 + 64 + (tid >> 2)) * K + (tid & 3) * 8;
    const unsigned short* bS0 = Bt + (n0 + (tid >> 2)) * K + (tid & 3) * 8;
    const unsigned short* bS1 = Bt + (n0 + 64 + (tid >> 2)) * K + (tid & 3) * 8;

#define GSTAGE(bufi, k0)                                   \
    {                                                      \
        gld_lds16(aS0 + (k0), &AsL[bufi][wid * 512]);      \
        gld_lds16(aS1 + (k0), &AsL[bufi][2048 + wid * 512]);\
        gld_lds16(bS0 + (k0), &BsL[bufi][wid * 512]);      \
        gld_lds16(bS1 + (k0), &BsL[bufi][2048 + wid * 512]);\
    }

#define GCOMPUTE(cur)                                                          \
    {                                                                          \
        u16x8 af[4], bfr[4];                                                   \
        _Pragma("unroll")                                                      \
        for (int i = 0; i < 4; i++) {                                          \
            af[i]  = *(const u16x8*)&AsL[cur][(wm * 64 + i * 16 + lr) * 32 + lg * 8]; \
            bfr[i] = *(const u16x8*)&BsL[cur][(wn * 64 + i * 16 + lr) * 32 + lg * 8]; \
        }                                                                      \
        _Pragma("unroll")                                                      \
        for (int i = 0; i < 4; i++)                                            \
            _Pragma("unroll")                                                  \
            for (int j = 0; j < 4; j++)                                        \
                acc[i][j] = mfma16(af[i], bfr[j], acc[i][j]);                  \
    }

    const int nk = K >> 5;
    GSTAGE(0, 0);
    __syncthreads();
    for (int t = 0; t < nk - 1; t++) {
        const int cur = t & 1;
        GSTAGE(cur ^ 1, (t + 1) * 32);
        GCOMPUTE(cur);
        __syncthreads();
    }
    GCOMPUTE((nk - 1) & 1);
#undef GSTAGE
#undef GCOMPUTE

#pragma unroll
    for (int i = 0; i < 4; i++)
#pragma unroll
        for (int j = 0; j < 4; j++)
#pragma unroll
            for (int r = 0; r < 4; r++) {
                long row = m0 + wm * 64 + i * 16 + lg * 4 + r;
                long col = n0 + wn * 64 + j * 16 + lr;
                float v = acc[i][j][r];
                if (MASKED) {
                    if (!mask[row]) v = 0.0f;
                    ((float*)Cv)[row * N + col] = v;
                } else if (WRITE_BF16) {
                    ((unsigned short*)Cv)[row * N + col] = f2bf(v);
                } else {
                    ((float*)Cv)[row * N + col] = v;
                }
            }
}

// ---------------- flash attention (no-max exp2 softmax, MFMA row-sum) ----------------
// grid (Nseq/64, H, B), 64 threads = 1 wave; wave owns 64 q-rows (u=0..3); KV tile = 64.
// Single-wave block: __syncthreads is wave-local (no partner stall); 4 blocks/CU.
__global__ __launch_bounds__(64) void attn_kernel(const unsigned short* __restrict__ qk,
                                                  const unsigned short* __restrict__ vT,
                                                  unsigned short* __restrict__ res) {
    const int Nseq = 2048, LD = 1024;
    const long T = 8192;
    const int qt = blockIdx.x, h = blockIdx.y, b = blockIdx.z;
    const int lane = threadIdx.x;
    const int lg = lane >> 4, lr = lane & 15;

    __shared__ unsigned short KsL[2][4096];   // [buf][64 kv][64 d] granule-swizzled
    __shared__ unsigned short VsL[2][4096];   // [buf][64 d][64 kv] granule-swizzled
    __shared__ unsigned int   Ps[4][512];     // [u][16q * 64kv bf16] XOR-swizzled

    // ---- Q fragments (64 q-rows: u=0..3) ----
    const int qbase = qt * 64;
    u16x8 qf[4][2];
#pragma unroll
    for (int u = 0; u < 4; u++) {
        long qrow = (long)b * Nseq + qbase + u * 16 + lr;
        qf[u][0] = *(const u16x8*)(qk + qrow * LD + h * 64 + lg * 8);
        qf[u][1] = *(const u16x8*)(qk + qrow * LD + h * 64 + 32 + lg * 8);
    }

    f32x4 oacc[4][4] = {};   // [u][nb]: O^T, lane holds q=lr, d = nb*16 + lg*4 + r
    f32x4 lacc[4] = {};
    u16x8 onesf;
#pragma unroll
    for (int e = 0; e < 8; e++) onesf[e] = 0x3F80;  // bf16 1.0

    // ---- staging (64 lanes, 8 granule-groups of 8 rows per tile) ----
    // granule G = 64g + lane: row R = 8g + (lane>>3), slot p = lane&7,
    // content granule = p ^ (R&7) = p ^ (lane>>3)
    const int R0 = lane >> 3, p0 = lane & 7;
    const int psw8 = (p0 ^ R0) * 8;
    const unsigned short* kS = qk + 512 + ((long)b * Nseq + R0) * LD + h * 64 + psw8;
    const unsigned short* vS = vT + ((long)h * 64 + R0) * T + (long)b * Nseq + psw8;

    const int swz = (lr & 7) << 2;   // Ps dword-index XOR (bits 2..4)
    const int rsw = lr & 7;          // K/V granule read swizzle

#define STAGE(bufi)                                                      \
    {                                                                    \
        _Pragma("unroll")                                                \
        for (int g = 0; g < 8; g++) {                                    \
            gld_lds16(kS + (long)(8 * g) * LD, &KsL[bufi][g * 512]);     \
            gld_lds16(vS + (long)(8 * g) * T,  &VsL[bufi][g * 512]);     \
        }                                                                \
        kS += 64L * LD; vS += 64;                                        \
    }

#define COMPUTE(cur)                                                                   \
    {                                                                                  \
        const unsigned short* Kb = &KsL[cur][0];                                       \
        const unsigned short* Vb = &VsL[cur][0];                                       \
        u16x8 kf0[4], kf1[4];                                                          \
        _Pragma("unroll")                                                              \
        for (int nb = 0; nb < 4; nb++) {                                               \
            int R = nb * 16 + lr;                                                      \
            kf0[nb] = *(const u16x8*)&Kb[R * 64 + ((lg ^ rsw) * 8)];                   \
            kf1[nb] = *(const u16x8*)&Kb[R * 64 + (((4 | lg) ^ rsw) * 8)];             \
        }                                                                              \
        /* phase A: QK^T -> exp2 -> pack -> P store, per u */                          \
        _Pragma("unroll")                                                              \
        for (int u = 0; u < 4; u++) {                                                  \
            f32x4 s[4];                                                                \
            __builtin_amdgcn_s_setprio(1);                                             \
            _Pragma("unroll")                                                          \
            for (int nb = 0; nb < 4; nb++) {                                           \
                f32x4 z = {};                                                          \
                z = mfma16(kf0[nb], qf[u][0], z);                                      \
                s[nb] = mfma16(kf1[nb], qf[u][1], z);                                  \
            }                                                                          \
            __builtin_amdgcn_s_setprio(0);                                             \
            unsigned int* Pw = &Ps[u][0];                                              \
            _Pragma("unroll")                                                          \
            for (int nb = 0; nb < 4; nb++) {                                           \
                uint2 pk2;                                                             \
                pk2.x = pkbf(fexp2(s[nb][0]), fexp2(s[nb][1]));                        \
                pk2.y = pkbf(fexp2(s[nb][2]), fexp2(s[nb][3]));                        \
                *(uint2*)&Pw[lr * 32 + ((8 * nb + 2 * lg) ^ swz)] = pk2;               \
            }                                                                          \
        }                                                                              \
        /* phase B: V frags once, then P read + lacc + PV per u */                     \
        u16x8 vf0[4], vf1[4];                                                          \
        _Pragma("unroll")                                                              \
        for (int nb = 0; nb < 4; nb++) {                                               \
            int R = nb * 16 + lr;                                                      \
            vf0[nb] = *(const u16x8*)&Vb[R * 64 + ((lg ^ rsw) * 8)];                   \
            vf1[nb] = *(const u16x8*)&Vb[R * 64 + (((4 | lg) ^ rsw) * 8)];             \
        }                                                                              \
        _Pragma("unroll")                                                              \
        for (int u = 0; u < 4; u++) {                                                  \
            const unsigned int* Pw = &Ps[u][0];                                        \
            u16x8 pa = __builtin_bit_cast(u16x8, *(const uint4*)&Pw[lr * 32 + ((4 * lg) ^ swz)]);      \
            u16x8 pb = __builtin_bit_cast(u16x8, *(const uint4*)&Pw[lr * 32 + ((16 + 4 * lg) ^ swz)]); \
            __builtin_amdgcn_s_setprio(1);                                             \
            lacc[u] = mfma16(onesf, pa, lacc[u]);                                      \
            lacc[u] = mfma16(onesf, pb, lacc[u]);                                      \
            _Pragma("unroll")                                                          \
            for (int nb = 0; nb < 4; nb++) {                                           \
                oacc[u][nb] = mfma16(vf0[nb], pa, oacc[u][nb]);                        \
                oacc[u][nb] = mfma16(vf1[nb], pb, oacc[u][nb]);                        \
            }                                                                          \
            __builtin_amdgcn_s_setprio(0);                                             \
        }                                                                              \
    }

    STAGE(0);
    __syncthreads();
    for (int t = 0; t < 31; t++) {
        const int cur = t & 1;
        STAGE(cur ^ 1);     // issue next tile DMA; drains at end-of-iter barrier
        COMPUTE(cur);
        __syncthreads();    // wave-local: vmcnt(0)+lgkmcnt(0) drain only
    }
    COMPUTE(1);

#undef STAGE
#undef COMPUTE

#pragma unroll
    for (int u = 0; u < 4; u++) {
        float inv = 1.0f / lacc[u][0];
        long qrow = (long)b * Nseq + qbase + u * 16 + lr;
#pragma unroll
        for (int nb = 0; nb < 4; nb++) {
            u16x4 st;
#pragma unroll
            for (int r = 0; r < 4; r++) st[r] = f2bf(oacc[u][nb][r] * inv);
            *(u16x4*)&res[qrow * 512 + h * 64 + nb * 16 + lg * 4] = st;
        }
    }
}

extern "C" void kernel_launch(void* const* d_in, const int* in_sizes, int n_in,
                              void* d_out, int out_size, void* d_ws, size_t ws_size,
                              hipStream_t stream) {
    const float* x   = (const float*)d_in[0];
    const int* mask  = (const int*)d_in[1];
    const float* Wq  = (const float*)d_in[2];
    const float* Wkv = (const float*)d_in[3];
    const float* Wo  = (const float*)d_in[4];
    float* out = (float*)d_out;

    const int Nseq = 2048, D = 512;
    const long T = 8192;
    const float QSCALE = 0.125f * 1.4426950408889634f;  // d^-0.5 * log2(e)

    unsigned short* ws    = (unsigned short*)d_ws;
    unsigned short* xb    = ws;                          // T*512
    unsigned short* WqkvT = xb    + T * D;               // 1536*512
    unsigned short* WoT   = WqkvT + 1536L * 512;         // 512*512
    unsigned short* qkb   = WoT   + 512L * 512;          // T*1024
    unsigned short* vTb   = qkb   + T * 1024;            // 512*T
    unsigned short* resb  = vTb   + 512L * T;            // T*512

    cvt_f32_bf16<<<(int)(T * D / 1024), 256, 0, stream>>>(x, xb, T * D);
    prep_weights<<<4096, 256, 0, stream>>>(Wq, Wkv, Wo, WqkvT, WoT, QSCALE);

    // qk = x @ [Wq*a | Wk]   (M=T, N=1024, K=512)
    gemm_bt<1, 0><<<dim3(8, 64), 256, 0, stream>>>(xb, WqkvT, qkb, T, 1024, D, nullptr);
    // vT = Wv^T x^T          (M=512, N=T, K=512)
    gemm_bt<1, 0><<<dim3(64, 4), 256, 0, stream>>>(WqkvT + 1024L * 512, xb, vTb, D, T, D, nullptr);

    attn_kernel<<<dim3(Nseq / 64, 8, 4), 64, 0, stream>>>(qkb, vTb, resb);

    // out = mask ? res @ Wo : 0
    gemm_bt<0, 1><<<dim3(4, 64), 256, 0, stream>>>(resb, WoT, out, T, D, D, mask);
}

// Round 8
// 122.504 us; speedup vs baseline: 1.1095x; 1.1095x over previous
//
#include <hip/hip_runtime.h>

typedef __bf16 bf16x8 __attribute__((ext_vector_type(8)));
typedef float f32x4 __attribute__((ext_vector_type(4)));
typedef float f32x16 __attribute__((ext_vector_type(16)));
typedef unsigned short u16x8 __attribute__((ext_vector_type(8)));
typedef unsigned short u16x4 __attribute__((ext_vector_type(4)));
typedef unsigned int u32x4 __attribute__((ext_vector_type(4)));
typedef int i32x2 __attribute__((ext_vector_type(2)));

__device__ inline unsigned short f2bf(float f) {
    __bf16 h = (__bf16)f;
    return __builtin_bit_cast(unsigned short, h);
}

__device__ inline unsigned int pkbf(float lo, float hi) {
    return (unsigned int)f2bf(lo) | ((unsigned int)f2bf(hi) << 16);
}

__device__ inline float fexp2(float x) {
#if __has_builtin(__builtin_amdgcn_exp2f)
    return __builtin_amdgcn_exp2f(x);
#else
    return exp2f(x);
#endif
}

__device__ inline f32x4 mfma16(u16x8 a, u16x8 b, f32x4 c) {
    return __builtin_amdgcn_mfma_f32_16x16x32_bf16(
        __builtin_bit_cast(bf16x8, a), __builtin_bit_cast(bf16x8, b), c, 0, 0, 0);
}

__device__ inline f32x16 mfma32(u16x8 a, u16x8 b, f32x16 c) {
    return __builtin_amdgcn_mfma_f32_32x32x16_bf16(
        __builtin_bit_cast(bf16x8, a), __builtin_bit_cast(bf16x8, b), c, 0, 0, 0);
}

// permlane32_swap: r[0] = {a.lo, b.lo-from-partner}, r[1] = {a.hi-from-partner, b.hi}
// lane<32: r0 = own a, r1 = partner's a.  lane>=32: r0 = partner's b, r1 = own b.
__device__ inline i32x2 permswap(unsigned int a, unsigned int b, int hi) {
#if __has_builtin(__builtin_amdgcn_permlane32_swap)
    (void)hi;
    return __builtin_amdgcn_permlane32_swap((int)a, (int)b, false, false);
#else
    int pa_ = __shfl_xor((int)a, 32);
    int pb_ = __shfl_xor((int)b, 32);
    i32x2 r;
    r[0] = hi ? pb_ : (int)a;
    r[1] = hi ? (int)b : pa_;
    return r;
#endif
}

// async global->LDS, 16B per lane; LDS dest is wave-uniform base (+lane*16 by HW)
__device__ inline void gld_lds16(const unsigned short* gsrc, unsigned short* ldst) {
    __builtin_amdgcn_global_load_lds(
        (const __attribute__((address_space(1))) unsigned int*)gsrc,
        (__attribute__((address_space(3))) unsigned int*)ldst, 16, 0, 0);
}

// ---------------- elementwise f32 -> bf16 ----------------
__global__ __launch_bounds__(256) void cvt_f32_bf16(const float* __restrict__ in,
                                                    unsigned short* __restrict__ out, long n) {
    long i = ((long)blockIdx.x * blockDim.x + threadIdx.x) * 4;
    if (i >= n) return;
    float4 v = *(const float4*)(in + i);
    ushort4 r;
    r.x = f2bf(v.x); r.y = f2bf(v.y); r.z = f2bf(v.z); r.w = f2bf(v.w);
    *(ushort4*)(out + i) = r;
}

// ---------------- weight transposes ----------------
// WqkvT rows: 0-511 = Wq^T * qscale, 512-1023 = Wk^T, 1024-1535 = Wv^T. WoT: Wo^T.
__global__ __launch_bounds__(256) void prep_weights(const float* __restrict__ Wq,
                                                    const float* __restrict__ Wkv,
                                                    const float* __restrict__ Wo,
                                                    unsigned short* __restrict__ WqkvT,
                                                    unsigned short* __restrict__ WoT,
                                                    float qscale) {
    int idx = blockIdx.x * 256 + threadIdx.x;
    const int NQKV = 1536 * 512;
    if (idx < NQKV) {
        int n = idx >> 9, kk = idx & 511;
        float v;
        if (n < 512) v = Wq[kk * 512 + n] * qscale;
        else         v = Wkv[kk * 1024 + (n - 512)];
        WqkvT[idx] = f2bf(v);
    } else {
        int j = idx - NQKV;
        int n = j >> 9, kk = j & 511;
        WoT[j] = f2bf(Wo[kk * 512 + n]);
    }
}

// ---------------- GEMM: C[m][n] = sum_k A[m][k] * Bt[n][k] ----------------
// 128x128 tile, BK=32, 4 waves, double-buffered linear LDS, global_load_lds staging.
template<int WRITE_BF16, int MASKED>
__global__ __launch_bounds__(256) void gemm_bt(const unsigned short* __restrict__ A,
                                               const unsigned short* __restrict__ Bt,
                                               void* __restrict__ Cv,
                                               int M, int N, int K,
                                               const int* __restrict__ mask) {
    __shared__ unsigned short AsL[2][128 * 32];
    __shared__ unsigned short BsL[2][128 * 32];
    const int tid = threadIdx.x;
    const int lane = tid & 63;
    const int wid = tid >> 6;
    const int lg = lane >> 4, lr = lane & 15;
    const int wm = wid >> 1, wn = wid & 1;
    const long m0 = (long)blockIdx.y * 128, n0 = (long)blockIdx.x * 128;

    f32x4 acc[4][4] = {};

    const unsigned short* aS0 = A  + (m0 + (tid >> 2)) * K + (tid & 3) * 8;
    const unsigned short* aS1 = A  + (m0 + 64 + (tid >> 2)) * K + (tid & 3) * 8;
    const unsigned short* bS0 = Bt + (n0 + (tid >> 2)) * K + (tid & 3) * 8;
    const unsigned short* bS1 = Bt + (n0 + 64 + (tid >> 2)) * K + (tid & 3) * 8;

#define GSTAGE(bufi, k0)                                   \
    {                                                      \
        gld_lds16(aS0 + (k0), &AsL[bufi][wid * 512]);      \
        gld_lds16(aS1 + (k0), &AsL[bufi][2048 + wid * 512]);\
        gld_lds16(bS0 + (k0), &BsL[bufi][wid * 512]);      \
        gld_lds16(bS1 + (k0), &BsL[bufi][2048 + wid * 512]);\
    }

#define GCOMPUTE(cur)                                                          \
    {                                                                          \
        u16x8 af[4], bfr[4];                                                   \
        _Pragma("unroll")                                                      \
        for (int i = 0; i < 4; i++) {                                          \
            af[i]  = *(const u16x8*)&AsL[cur][(wm * 64 + i * 16 + lr) * 32 + lg * 8]; \
            bfr[i] = *(const u16x8*)&BsL[cur][(wn * 64 + i * 16 + lr) * 32 + lg * 8]; \
        }                                                                      \
        _Pragma("unroll")                                                      \
        for (int i = 0; i < 4; i++)                                            \
            _Pragma("unroll")                                                  \
            for (int j = 0; j < 4; j++)                                        \
                acc[i][j] = mfma16(af[i], bfr[j], acc[i][j]);                  \
    }

    const int nk = K >> 5;
    GSTAGE(0, 0);
    __syncthreads();
    for (int t = 0; t < nk - 1; t++) {
        const int cur = t & 1;
        GSTAGE(cur ^ 1, (t + 1) * 32);
        GCOMPUTE(cur);
        __syncthreads();
    }
    GCOMPUTE((nk - 1) & 1);
#undef GSTAGE
#undef GCOMPUTE

#pragma unroll
    for (int i = 0; i < 4; i++)
#pragma unroll
        for (int j = 0; j < 4; j++)
#pragma unroll
            for (int r = 0; r < 4; r++) {
                long row = m0 + wm * 64 + i * 16 + lg * 4 + r;
                long col = n0 + wn * 64 + j * 16 + lr;
                float v = acc[i][j][r];
                if (MASKED) {
                    if (!mask[row]) v = 0.0f;
                    ((float*)Cv)[row * N + col] = v;
                } else if (WRITE_BF16) {
                    ((unsigned short*)Cv)[row * N + col] = f2bf(v);
                } else {
                    ((float*)Cv)[row * N + col] = v;
                }
            }
}

// ---------------- flash attention: 32x32 MFMA, in-register P via permlane ----------------
// grid (Nseq/64, H, B), 128 threads = 2 waves; wave owns 32 q-rows; KV tile = 64.
// QK^T swapped (A=K, B=Q): lane holds col q=lane&31, rows crow(reg,hi).
// P->bf16 in-register: 16 cvt_pk + 8 permlane32_swap build PV A-fragments. No P LDS.
__global__ __launch_bounds__(128) void attn_kernel(const unsigned short* __restrict__ qk,
                                                   const unsigned short* __restrict__ vT,
                                                   unsigned short* __restrict__ res) {
    const int Nseq = 2048, LD = 1024;
    const long T = 8192;
    const int qt = blockIdx.x, h = blockIdx.y, b = blockIdx.z;
    const int tid = threadIdx.x;
    const int wid = tid >> 6, lane = tid & 63;
    const int qL = lane & 31, hi = lane >> 5;

    __shared__ unsigned short KsL[2][4096];   // [buf][64 kv][64 d] granule-swizzled
    __shared__ unsigned short VsL[2][4096];   // [buf][64 d][64 kv] granule-swizzled
    __shared__ float l_lds[64];

    // ---- Q fragments: B-operand, lane n=q=qL, k-chunk j: d = 16j + 8hi + e ----
    const int qbase = qt * 64 + wid * 32;
    const long qrow = (long)b * Nseq + qbase + qL;
    u16x8 qf[4];
#pragma unroll
    for (int j = 0; j < 4; j++)
        qf[j] = *(const u16x8*)(qk + qrow * LD + h * 64 + 16 * j + 8 * hi);

    f32x16 oacc[2] = {};     // [db]: O[q=crow(reg,hi)][d=db*32+qL]
    float lsum = 0.0f;

    // ---- staging: wave0 -> K tile, wave1 -> V tile (granule-swizzled source) ----
    const int R0 = lane >> 3, p0 = lane & 7;
    const int psw8 = (p0 ^ R0) * 8;
    const unsigned short* kS = qk + 512 + ((long)b * Nseq + R0) * LD + h * 64 + psw8;
    const unsigned short* vS = vT + ((long)h * 64 + R0) * T + (long)b * Nseq + psw8;

    const int rsw = qL & 7;   // read-side granule swizzle (row & 7)

#define STAGE(bufi)                                                          \
    {                                                                        \
        if (wid == 0) {                                                      \
            _Pragma("unroll")                                                \
            for (int g = 0; g < 8; g++)                                      \
                gld_lds16(kS + (long)(8 * g) * LD, &KsL[bufi][g * 512]);     \
        } else {                                                             \
            _Pragma("unroll")                                                \
            for (int g = 0; g < 8; g++)                                      \
                gld_lds16(vS + (long)(8 * g) * T, &VsL[bufi][g * 512]);      \
        }                                                                    \
        kS += 64L * LD; vS += 64;                                            \
    }

#define COMPUTE(cur)                                                                   \
    {                                                                                  \
        const unsigned short* Kb = &KsL[cur][0];                                       \
        const unsigned short* Vb = &VsL[cur][0];                                       \
        u16x8 pa[4];                                                                   \
        _Pragma("unroll")                                                              \
        for (int kvb = 0; kvb < 2; kvb++) {                                            \
            f32x16 s = {};                                                             \
            const int krow = kvb * 32 + qL;                                            \
            __builtin_amdgcn_s_setprio(1);                                             \
            _Pragma("unroll")                                                          \
            for (int j = 0; j < 4; j++) {                                              \
                u16x8 ka = *(const u16x8*)&Kb[krow * 64 + (((2 * j + hi) ^ rsw) * 8)]; \
                s = mfma32(ka, qf[j], s);                                              \
            }                                                                          \
            __builtin_amdgcn_s_setprio(0);                                             \
            float e0, e1;                                                              \
            unsigned int w[8];                                                         \
            _Pragma("unroll")                                                          \
            for (int i = 0; i < 8; i++) {                                              \
                e0 = fexp2(s[2 * i]); e1 = fexp2(s[2 * i + 1]);                        \
                lsum += e0 + e1;                                                       \
                w[i] = pkbf(e0, e1);                                                   \
            }                                                                          \
            _Pragma("unroll")                                                          \
            for (int hh = 0; hh < 2; hh++) {                                           \
                i32x2 ra = permswap(w[4 * hh + 0], w[4 * hh + 2], hi);                 \
                i32x2 rb = permswap(w[4 * hh + 1], w[4 * hh + 3], hi);                 \
                u32x4 fw;                                                              \
                fw[0] = (unsigned)ra[0]; fw[1] = (unsigned)rb[0];                      \
                fw[2] = (unsigned)ra[1]; fw[3] = (unsigned)rb[1];                      \
                pa[kvb * 2 + hh] = __builtin_bit_cast(u16x8, fw);                      \
            }                                                                          \
        }                                                                              \
        __builtin_amdgcn_s_setprio(1);                                                 \
        _Pragma("unroll")                                                              \
        for (int db = 0; db < 2; db++) {                                               \
            const int vrow = db * 32 + qL;                                             \
            _Pragma("unroll")                                                          \
            for (int jk = 0; jk < 4; jk++) {                                           \
                u16x8 vb = *(const u16x8*)&Vb[vrow * 64 + (((2 * jk + hi) ^ rsw) * 8)];\
                oacc[db] = mfma32(pa[jk], vb, oacc[db]);                               \
            }                                                                          \
        }                                                                              \
        __builtin_amdgcn_s_setprio(0);                                                 \
    }

    STAGE(0);
    __syncthreads();
    for (int t = 0; t < 31; t++) {
        const int cur = t & 1;
        STAGE(cur ^ 1);     // issue next tile DMA; drains at end-of-iter barrier
        COMPUTE(cur);
        __syncthreads();
    }
    COMPUTE(1);

#undef STAGE
#undef COMPUTE

    // ---- epilogue: l broadcast + normalize + store ----
    float lpart = __shfl_xor(lsum, 32);
    float linv = 1.0f / (lsum + lpart);
    if (lane < 32) l_lds[wid * 32 + qL] = linv;
    __syncthreads();

#pragma unroll
    for (int reg = 0; reg < 16; reg++) {
        const int crow = (reg & 3) + 8 * (reg >> 2) + 4 * hi;
        float invr = l_lds[wid * 32 + crow];
        long row = (long)b * Nseq + qbase + crow;
#pragma unroll
        for (int db = 0; db < 2; db++)
            res[row * 512 + h * 64 + db * 32 + qL] = f2bf(oacc[db][reg] * invr);
    }
}

extern "C" void kernel_launch(void* const* d_in, const int* in_sizes, int n_in,
                              void* d_out, int out_size, void* d_ws, size_t ws_size,
                              hipStream_t stream) {
    const float* x   = (const float*)d_in[0];
    const int* mask  = (const int*)d_in[1];
    const float* Wq  = (const float*)d_in[2];
    const float* Wkv = (const float*)d_in[3];
    const float* Wo  = (const float*)d_in[4];
    float* out = (float*)d_out;

    const int Nseq = 2048, D = 512;
    const long T = 8192;
    const float QSCALE = 0.125f * 1.4426950408889634f;  // d^-0.5 * log2(e)

    unsigned short* ws    = (unsigned short*)d_ws;
    unsigned short* xb    = ws;                          // T*512
    unsigned short* WqkvT = xb    + T * D;               // 1536*512
    unsigned short* WoT   = WqkvT + 1536L * 512;         // 512*512
    unsigned short* qkb   = WoT   + 512L * 512;          // T*1024
    unsigned short* vTb   = qkb   + T * 1024;            // 512*T
    unsigned short* resb  = vTb   + 512L * T;            // T*512

    cvt_f32_bf16<<<(int)(T * D / 1024), 256, 0, stream>>>(x, xb, T * D);
    prep_weights<<<4096, 256, 0, stream>>>(Wq, Wkv, Wo, WqkvT, WoT, QSCALE);

    // qk = x @ [Wq*a | Wk]   (M=T, N=1024, K=512)
    gemm_bt<1, 0><<<dim3(8, 64), 256, 0, stream>>>(xb, WqkvT, qkb, T, 1024, D, nullptr);
    // vT = Wv^T x^T          (M=512, N=T, K=512)
    gemm_bt<1, 0><<<dim3(64, 4), 256, 0, stream>>>(WqkvT + 1024L * 512, xb, vTb, D, T, D, nullptr);

    attn_kernel<<<dim3(Nseq / 64, 8, 4), 128, 0, stream>>>(qkb, vTb, resb);

    // out = mask ? res @ Wo : 0
    gemm_bt<0, 1><<<dim3(4, 64), 256, 0, stream>>>(resb, WoT, out, T, D, D, mask);
}

// Round 9
// 112.132 us; speedup vs baseline: 1.2122x; 1.0925x over previous
//
#include <hip/hip_runtime.h>

typedef __bf16 bf16x8 __attribute__((ext_vector_type(8)));
typedef float f32x4 __attribute__((ext_vector_type(4)));
typedef float f32x16 __attribute__((ext_vector_type(16)));
typedef unsigned short u16x8 __attribute__((ext_vector_type(8)));
typedef unsigned int u32x4 __attribute__((ext_vector_type(4)));
typedef int i32x2 __attribute__((ext_vector_type(2)));

__device__ inline unsigned short f2bf(float f) {
    __bf16 h = (__bf16)f;
    return __builtin_bit_cast(unsigned short, h);
}

__device__ inline unsigned int pkbf(float lo, float hi) {
    return (unsigned int)f2bf(lo) | ((unsigned int)f2bf(hi) << 16);
}

__device__ inline float fexp2(float x) {
#if __has_builtin(__builtin_amdgcn_exp2f)
    return __builtin_amdgcn_exp2f(x);
#else
    return exp2f(x);
#endif
}

__device__ inline f32x4 mfma16(u16x8 a, u16x8 b, f32x4 c) {
    return __builtin_amdgcn_mfma_f32_16x16x32_bf16(
        __builtin_bit_cast(bf16x8, a), __builtin_bit_cast(bf16x8, b), c, 0, 0, 0);
}

__device__ inline f32x16 mfma32(u16x8 a, u16x8 b, f32x16 c) {
    return __builtin_amdgcn_mfma_f32_32x32x16_bf16(
        __builtin_bit_cast(bf16x8, a), __builtin_bit_cast(bf16x8, b), c, 0, 0, 0);
}

__device__ inline i32x2 permswap(unsigned int a, unsigned int b, int hi) {
#if __has_builtin(__builtin_amdgcn_permlane32_swap)
    (void)hi;
    return __builtin_amdgcn_permlane32_swap((int)a, (int)b, false, false);
#else
    int pa_ = __shfl_xor((int)a, 32);
    int pb_ = __shfl_xor((int)b, 32);
    i32x2 r;
    r[0] = hi ? pb_ : (int)a;
    r[1] = hi ? (int)b : pa_;
    return r;
#endif
}

__device__ inline void gld_lds16(const unsigned short* gsrc, unsigned short* ldst) {
    __builtin_amdgcn_global_load_lds(
        (const __attribute__((address_space(1))) unsigned int*)gsrc,
        (__attribute__((address_space(3))) unsigned int*)ldst, 16, 0, 0);
}

#define WAIT_VM(n)                                          \
    asm volatile("s_waitcnt vmcnt(" #n ")" ::: "memory");   \
    __builtin_amdgcn_sched_barrier(0)
#define WAIT_LGKM0                                          \
    asm volatile("s_waitcnt lgkmcnt(0)" ::: "memory");      \
    __builtin_amdgcn_sched_barrier(0)
#define BARRIER                                             \
    __builtin_amdgcn_s_barrier();                           \
    __builtin_amdgcn_sched_barrier(0)

// ---------------- elementwise f32 -> bf16 ----------------
__global__ __launch_bounds__(256) void cvt_f32_bf16(const float* __restrict__ in,
                                                    unsigned short* __restrict__ out, long n) {
    long i = ((long)blockIdx.x * blockDim.x + threadIdx.x) * 4;
    if (i >= n) return;
    float4 v = *(const float4*)(in + i);
    ushort4 r;
    r.x = f2bf(v.x); r.y = f2bf(v.y); r.z = f2bf(v.z); r.w = f2bf(v.w);
    *(ushort4*)(out + i) = r;
}

// ---------------- tiled transpose: W (K,N) f32 -> Wt (N,K) bf16, * scale ----------------
__global__ __launch_bounds__(256) void transpose_cvt_tiled(const float* __restrict__ W,
                                                           unsigned short* __restrict__ Wt,
                                                           int K, int N, float scale) {
    __shared__ float tile[64][65];
    const int n0 = blockIdx.x * 64, k0 = blockIdx.y * 64;
    const int c = threadIdx.x & 63;
    const int r4 = threadIdx.x >> 6;
#pragma unroll
    for (int i = 0; i < 16; i++) {
        int r = r4 * 16 + i;
        tile[r][c] = W[(long)(k0 + r) * N + n0 + c];
    }
    __syncthreads();
#pragma unroll
    for (int i = 0; i < 16; i++) {
        int rr = r4 * 16 + i;
        Wt[(long)(n0 + rr) * K + k0 + c] = f2bf(tile[c][rr] * scale);
    }
}

// ---------------- GEMM: C[m][n] = sum_k A[m][k] * Bt[n][k] ----------------
// 128x128 tile, BK=32, 4 waves, dbuf LDS, counted-vmcnt 2-barrier pipeline.
template<int WRITE_BF16, int MASKED>
__global__ __launch_bounds__(256) void gemm_bt(const unsigned short* __restrict__ A,
                                               const unsigned short* __restrict__ Bt,
                                               void* __restrict__ Cv,
                                               int M, int N, int K,
                                               const int* __restrict__ mask) {
    __shared__ unsigned short AsL[2][128 * 32];
    __shared__ unsigned short BsL[2][128 * 32];
    const int tid = threadIdx.x;
    const int lane = tid & 63;
    const int wid = tid >> 6;
    const int lg = lane >> 4, lr = lane & 15;
    const int wm = wid >> 1, wn = wid & 1;
    const long m0 = (long)blockIdx.y * 128, n0 = (long)blockIdx.x * 128;

    f32x4 acc[4][4] = {};

    const unsigned short* aS0 = A  + (m0 + (tid >> 2)) * K + (tid & 3) * 8;
    const unsigned short* aS1 = A  + (m0 + 64 + (tid >> 2)) * K + (tid & 3) * 8;
    const unsigned short* bS0 = Bt + (n0 + (tid >> 2)) * K + (tid & 3) * 8;
    const unsigned short* bS1 = Bt + (n0 + 64 + (tid >> 2)) * K + (tid & 3) * 8;

#define GSTAGE(bufi, k0v)                                    \
    {                                                        \
        gld_lds16(aS0 + (k0v), &AsL[bufi][wid * 512]);       \
        gld_lds16(aS1 + (k0v), &AsL[bufi][2048 + wid * 512]);\
        gld_lds16(bS0 + (k0v), &BsL[bufi][wid * 512]);       \
        gld_lds16(bS1 + (k0v), &BsL[bufi][2048 + wid * 512]);\
    }

#define GREAD(cur)                                                                    \
    {                                                                                 \
        _Pragma("unroll")                                                             \
        for (int i = 0; i < 4; i++) {                                                 \
            af[i]  = *(const u16x8*)&AsL[cur][(wm * 64 + i * 16 + lr) * 32 + lg * 8]; \
            bfr[i] = *(const u16x8*)&BsL[cur][(wn * 64 + i * 16 + lr) * 32 + lg * 8]; \
        }                                                                             \
    }

#define GMFMA                                                                  \
    {                                                                          \
        _Pragma("unroll")                                                      \
        for (int i = 0; i < 4; i++)                                            \
            _Pragma("unroll")                                                  \
            for (int j = 0; j < 4; j++)                                        \
                acc[i][j] = mfma16(af[i], bfr[j], acc[i][j]);                  \
    }

    const int nk = K >> 5;
    GSTAGE(0, 0);
    GSTAGE(1, 32);
    for (int t = 0; t < nk - 1; t++) {
        const int cur = t & 1;
        u16x8 af[4], bfr[4];
        WAIT_VM(4);       // tile t landed (own 4 loads); t+1's stay in flight
        BARRIER;          // all waves' tile-t loads landed
        GREAD(cur);
        WAIT_LGKM0;       // reads complete
        BARRIER;          // all waves done reading tile t
        if (t < nk - 2) GSTAGE(cur, (t + 2) * 32);
        GMFMA;
    }
    {
        u16x8 af[4], bfr[4];
        WAIT_VM(0);
        BARRIER;
        GREAD((nk - 1) & 1);
        GMFMA;
    }
#undef GSTAGE
#undef GREAD
#undef GMFMA

#pragma unroll
    for (int i = 0; i < 4; i++)
#pragma unroll
        for (int j = 0; j < 4; j++)
#pragma unroll
            for (int r = 0; r < 4; r++) {
                long row = m0 + wm * 64 + i * 16 + lg * 4 + r;
                long col = n0 + wn * 64 + j * 16 + lr;
                float v = acc[i][j][r];
                if (MASKED) {
                    if (!mask[row]) v = 0.0f;
                    ((float*)Cv)[row * N + col] = v;
                } else if (WRITE_BF16) {
                    ((unsigned short*)Cv)[row * N + col] = f2bf(v);
                } else {
                    ((float*)Cv)[row * N + col] = v;
                }
            }
}

// ---------------- flash attention: 32x32 MFMA, in-register P, counted-vmcnt pipeline ----------------
// 1D grid 1024, XCD-group swizzle: all 32 q-tiles of one (b,h) on one XCD.
// 128 threads = 2 waves; wave owns 32 q-rows; KV tile = 64; wave0 stages K, wave1 stages V.
__global__ __launch_bounds__(128) void attn_kernel(const unsigned short* __restrict__ qk,
                                                   const unsigned short* __restrict__ vT,
                                                   unsigned short* __restrict__ res) {
    const int Nseq = 2048, LD = 1024;
    const long T = 8192;
    const int id = blockIdx.x;
    const int xcd = id & 7, jj = id >> 3;
    const int g = xcd + 8 * (jj & 3);       // group = h + 8*b, 4 groups per XCD
    const int qt = jj >> 2;
    const int b = g >> 3, h = g & 7;

    const int tid = threadIdx.x;
    const int wid = tid >> 6, lane = tid & 63;
    const int qL = lane & 31, hi = lane >> 5;

    __shared__ unsigned short KsL[2][4096];   // [buf][64 kv][64 d] granule-swizzled
    __shared__ unsigned short VsL[2][4096];   // [buf][64 d][64 kv] granule-swizzled
    __shared__ float l_lds[64];

    // ---- Q fragments: B-operand, lane n=q=qL, k-chunk j: d = 16j + 8hi + e ----
    const int qbase = qt * 64 + wid * 32;
    const long qrow = (long)b * Nseq + qbase + qL;
    u16x8 qf[4];
#pragma unroll
    for (int j = 0; j < 4; j++)
        qf[j] = *(const u16x8*)(qk + qrow * LD + h * 64 + 16 * j + 8 * hi);

    f32x16 oacc[2] = {};     // [db]: O[q=crow(reg,hi)][d=db*32+qL]
    float lsA = 0.0f, lsB = 0.0f;

    // ---- staging: wave0 -> K tile, wave1 -> V tile (granule-swizzled source) ----
    const int R0 = lane >> 3, p0 = lane & 7;
    const int psw8 = (p0 ^ R0) * 8;
    const unsigned short* kS = qk + 512 + ((long)b * Nseq + R0) * LD + h * 64 + psw8;
    const unsigned short* vS = vT + ((long)h * 64 + R0) * T + (long)b * Nseq + psw8;

    const int rsw = qL & 7;   // read-side granule swizzle (row & 7)

#define STAGE(bufi)                                                          \
    {                                                                        \
        if (wid == 0) {                                                      \
            _Pragma("unroll")                                                \
            for (int gg = 0; gg < 8; gg++)                                   \
                gld_lds16(kS + (long)(8 * gg) * LD, &KsL[bufi][gg * 512]);   \
        } else {                                                             \
            _Pragma("unroll")                                                \
            for (int gg = 0; gg < 8; gg++)                                   \
                gld_lds16(vS + (long)(8 * gg) * T, &VsL[bufi][gg * 512]);    \
        }                                                                    \
        kS += 64L * LD; vS += 64;                                            \
    }

#define READF(cur)                                                                     \
    {                                                                                  \
        const unsigned short* Kb = &KsL[cur][0];                                       \
        const unsigned short* Vb = &VsL[cur][0];                                       \
        _Pragma("unroll")                                                              \
        for (int kvb = 0; kvb < 2; kvb++) {                                            \
            const int krow = kvb * 32 + qL;                                            \
            _Pragma("unroll")                                                          \
            for (int j = 0; j < 4; j++)                                                \
                kf[kvb][j] = *(const u16x8*)&Kb[krow * 64 + (((2 * j + hi) ^ rsw) * 8)]; \
        }                                                                              \
        _Pragma("unroll")                                                              \
        for (int db = 0; db < 2; db++) {                                               \
            const int vrow = db * 32 + qL;                                             \
            _Pragma("unroll")                                                          \
            for (int jk = 0; jk < 4; jk++)                                             \
                vf[db][jk] = *(const u16x8*)&Vb[vrow * 64 + (((2 * jk + hi) ^ rsw) * 8)]; \
        }                                                                              \
    }

#define BODY                                                                           \
    {                                                                                  \
        u16x8 pa[4];                                                                   \
        _Pragma("unroll")                                                              \
        for (int kvb = 0; kvb < 2; kvb++) {                                            \
            f32x16 s = {};                                                             \
            __builtin_amdgcn_s_setprio(1);                                             \
            _Pragma("unroll")                                                          \
            for (int j = 0; j < 4; j++) s = mfma32(kf[kvb][j], qf[j], s);              \
            __builtin_amdgcn_s_setprio(0);                                             \
            unsigned int w[8];                                                         \
            _Pragma("unroll")                                                          \
            for (int i = 0; i < 8; i++) {                                              \
                float e0 = fexp2(s[2 * i]), e1 = fexp2(s[2 * i + 1]);                  \
                float t2 = e0 + e1;                                                    \
                if (i & 1) lsB += t2; else lsA += t2;                                  \
                w[i] = pkbf(e0, e1);                                                   \
            }                                                                          \
            _Pragma("unroll")                                                          \
            for (int hh = 0; hh < 2; hh++) {                                           \
                i32x2 ra = permswap(w[4 * hh + 0], w[4 * hh + 2], hi);                 \
                i32x2 rb = permswap(w[4 * hh + 1], w[4 * hh + 3], hi);                 \
                u32x4 fw;                                                              \
                fw[0] = (unsigned)ra[0]; fw[1] = (unsigned)rb[0];                      \
                fw[2] = (unsigned)ra[1]; fw[3] = (unsigned)rb[1];                      \
                pa[kvb * 2 + hh] = __builtin_bit_cast(u16x8, fw);                      \
            }                                                                          \
        }                                                                              \
        __builtin_amdgcn_s_setprio(1);                                                 \
        _Pragma("unroll")                                                              \
        for (int db = 0; db < 2; db++)                                                 \
            _Pragma("unroll")                                                          \
            for (int jk = 0; jk < 4; jk++)                                             \
                oacc[db] = mfma32(pa[jk], vf[db][jk], oacc[db]);                       \
        __builtin_amdgcn_s_setprio(0);                                                 \
    }

    STAGE(0);
    STAGE(1);
    for (int t = 0; t < 31; t++) {
        const int cur = t & 1;
        u16x8 kf[2][4], vf[2][4];
        WAIT_VM(8);       // own tile-t loads landed; t+1's 8 in flight
        BARRIER;          // partner's tile-t loads landed too
        READF(cur);
        WAIT_LGKM0;       // frag reads complete
        BARRIER;          // both waves done reading tile t
        if (t < 30) STAGE(cur);   // overwrite cur with tile t+2
        BODY;
    }
    {
        u16x8 kf[2][4], vf[2][4];
        WAIT_VM(0);
        BARRIER;
        READF(1);
        BODY;
    }
#undef STAGE
#undef READF
#undef BODY

    // ---- epilogue: l broadcast + normalize + store ----
    float lsum = lsA + lsB;
    float lpart = __shfl_xor(lsum, 32);
    float linv = 1.0f / (lsum + lpart);
    if (lane < 32) l_lds[wid * 32 + qL] = linv;
    __syncthreads();

#pragma unroll
    for (int reg = 0; reg < 16; reg++) {
        const int crow = (reg & 3) + 8 * (reg >> 2) + 4 * hi;
        float invr = l_lds[wid * 32 + crow];
        long row = (long)b * Nseq + qbase + crow;
#pragma unroll
        for (int db = 0; db < 2; db++)
            res[row * 512 + h * 64 + db * 32 + qL] = f2bf(oacc[db][reg] * invr);
    }
}

extern "C" void kernel_launch(void* const* d_in, const int* in_sizes, int n_in,
                              void* d_out, int out_size, void* d_ws, size_t ws_size,
                              hipStream_t stream) {
    const float* x   = (const float*)d_in[0];
    const int* mask  = (const int*)d_in[1];
    const float* Wq  = (const float*)d_in[2];
    const float* Wkv = (const float*)d_in[3];
    const float* Wo  = (const float*)d_in[4];
    float* out = (float*)d_out;

    const int Nseq = 2048, D = 512;
    const long T = 8192;
    const float QSCALE = 0.125f * 1.4426950408889634f;  // d^-0.5 * log2(e)

    unsigned short* ws    = (unsigned short*)d_ws;
    unsigned short* xb    = ws;                          // T*512
    unsigned short* WqkvT = xb    + T * D;               // 1536*512
    unsigned short* WoT   = WqkvT + 1536L * 512;         // 512*512
    unsigned short* qkb   = WoT   + 512L * 512;          // T*1024
    unsigned short* vTb   = qkb   + T * 1024;            // 512*T
    unsigned short* resb  = vTb   + 512L * T;            // T*512

    cvt_f32_bf16<<<(int)(T * D / 1024), 256, 0, stream>>>(x, xb, T * D);
    // tiled transposes (coalesced both sides)
    transpose_cvt_tiled<<<dim3(8, 8),  256, 0, stream>>>(Wq,  WqkvT,              D, 512,  QSCALE);
    transpose_cvt_tiled<<<dim3(16, 8), 256, 0, stream>>>(Wkv, WqkvT + 512L * 512, D, 1024, 1.0f);
    transpose_cvt_tiled<<<dim3(8, 8),  256, 0, stream>>>(Wo,  WoT,                D, 512,  1.0f);

    // qk = x @ [Wq*a | Wk]   (M=T, N=1024, K=512)
    gemm_bt<1, 0><<<dim3(8, 64), 256, 0, stream>>>(xb, WqkvT, qkb, T, 1024, D, nullptr);
    // vT = Wv^T x^T          (M=512, N=T, K=512)
    gemm_bt<1, 0><<<dim3(64, 4), 256, 0, stream>>>(WqkvT + 1024L * 512, xb, vTb, D, T, D, nullptr);

    attn_kernel<<<1024, 128, 0, stream>>>(qkb, vTb, resb);

    // out = mask ? res @ Wo : 0
    gemm_bt<0, 1><<<dim3(4, 64), 256, 0, stream>>>(resb, WoT, out, T, D, D, mask);
}